// Round 15
// baseline (1818.088 us; speedup 1.0000x reference)
//
#include <hip/hip_runtime.h>
#include <cstdint>
#include <cstddef>

typedef unsigned short u16;
typedef __attribute__((ext_vector_type(8))) short short8;
typedef __attribute__((ext_vector_type(4))) float f32x4;

static constexpr int BB = 16, DIN = 240, NN = 2048, TT = 2048;
static constexpr long long Y_SIZE = (long long)BB * DIN * TT;          // 7,864,320 f32
static constexpr float SQRT_HALF_F = 0.70710678118654752440f;
static constexpr int HPAD = 64;                 // zero-pad rows each side of h (max shift 54)
static constexpr int HROWS = NN + 2 * HPAD;     // 2176

#define DEVI __device__ __forceinline__

DEVI u16 f2bf(float f) {
    unsigned u = __builtin_bit_cast(unsigned, f);
    u += 0x7FFFu + ((u >> 16) & 1u);
    return (u16)(u >> 16);
}
DEVI float bf2f(u16 h) {
    unsigned u = ((unsigned)h) << 16;
    return __builtin_bit_cast(float, u);
}

DEVI void gld16(const void* g, const void* l) {
    __builtin_amdgcn_global_load_lds(
        (const __attribute__((address_space(1))) unsigned int*)g,
        (__attribute__((address_space(3))) unsigned int*)l, 16, 0, 0);
}

// GLU column permutation for the 128-col-tile geometry (gemm128glu): GEMM col g ->
// conv output channel. Block covers 128 GEMM cols -> 64 channels; within each
// wave's 64-col span, fragments n={0,2} are "a" and n={1,3} the gates (+512).
DEVI int glu_perm(int g) {
    int tile = g >> 7, r = g & 127;
    int wc2 = (r >> 6) & 1, r2 = r & 63;
    int n = r2 >> 4, fr = r2 & 15;
    return tile * 64 + wc2 * 32 + (n >> 1) * 16 + fr + (n & 1) * 512;
}

// ---------------- GEMM params ----------------
// C[row][col] = scale * sum_taps sum_k A[row+shift][k] * B[col][k]  (+bias)
struct GemmP {
    const u16* A; long long a_bstride; int lda;
    const u16* Bw; long long b_bstride; long long b_tapstride; int ldb;
    int ntaps; int shift0; int dshift; int Kt; int ks_log2;
    void* out; long long o_bstride; int ldc;
    const float* bias; int bias_bstride;
    float scale;
    int store_ncols;
};

#define FENCE() asm volatile("" ::: "memory")
#define SBAR()  do { FENCE(); __builtin_amdgcn_s_barrier(); FENCE(); } while (0)

// =============== 256x256 MFMA GEMM, 1-barrier K-tile, triple-buffered B ===============
// OUTK: 1 = bf16 row-major col-bias (+scale). 2 = f32 transposed col-bias, col-masked.
//       5 = bf16 row-bias.
// Requires tot (= ntaps << ks_log2) EVEN and >= 4. (Hazard audit: see r11.)
template <int OUTK>
__global__ __launch_bounds__(512, 2)
void gemm256(GemmP p, int tilesM, int tilesN) {
    __shared__ __align__(16) u16 As[2][256 * 64];
    __shared__ __align__(16) u16 Bs[3][256 * 64];   // 64K + 96K = 160 KiB exactly
    const int tid = threadIdx.x;
    const int lane = tid & 63;
    const int wv = tid >> 6;
    const int wr = wv >> 2, wcq = wv & 3;          // 2M x 4N wave grid
    const int fr = lane & 15, fq = lane >> 4;

    const int nwg = gridDim.x;
    int widx = (blockIdx.x & 7) * (nwg >> 3) + (blockIdx.x >> 3);
    const int mt = widx % tilesM; widx /= tilesM;
    const int nt = widx % tilesN;
    const int bz = widx / tilesN;
    const int n0 = mt * 256, c0 = nt * 256;

    const int lda = p.lda, ldb = p.ldb;
    const u16* Abase = p.A + (long long)bz * p.a_bstride;
    const u16* Bbase = p.Bw + (long long)bz * p.b_bstride;
    const int kmask = (1 << p.ks_log2) - 1;
    const int tot = p.ntaps << p.ks_log2;

    f32x4 acc[8][4];
#pragma unroll
    for (int m = 0; m < 8; ++m)
#pragma unroll
        for (int n = 0; n < 4; ++n) acc[m][n] = (f32x4){0.f, 0.f, 0.f, 0.f};

    const int srow = lane >> 3, sslot = lane & 7;
    const int js = (sslot ^ srow) << 3;
    const int sr0 = wv * 16 + srow;
    const int wvB = wv * 1024;

    const long long sA8 = 8LL * lda, sAh = 128LL * lda;
    const long long sB8 = 8LL * ldb, sBh = 128LL * ldb;
    const long long dAtap = (long long)p.dshift * lda - (long long)kmask * 64;
    const long long dBtap = p.b_tapstride - (long long)kmask * 64;

    auto aAddr = [&](int t) -> const u16* {
        int tap = t >> p.ks_log2;
        return Abase + (long long)(n0 + p.shift0 + tap * p.dshift + sr0) * lda
               + ((t & kmask) << 6) + js;
    };
    auto bAddr = [&](int t) -> const u16* {
        int tap = t >> p.ks_log2;
        return Bbase + (long long)tap * p.b_tapstride
               + (long long)(c0 + sr0) * ldb + ((t & kmask) << 6) + js;
    };

    u16* uA = &As[0][wvB];
    u16* pB0 = &Bs[0][0];
    u16* pB1 = &Bs[1][0];
    u16* pB2 = &Bs[2][0];

    {
        const u16* a0 = aAddr(0);
        gld16(a0, uA);              gld16(a0 + sA8, uA + 512);
        gld16(a0 + sAh, uA + 8192); gld16(a0 + sAh + sA8, uA + 8192 + 512);
        const u16* b0 = bAddr(0);
        u16* d0 = pB0 + wvB;
        gld16(b0, d0);              gld16(b0 + sB8, d0 + 512);
        gld16(b0 + sBh, d0 + 8192); gld16(b0 + sBh + sB8, d0 + 8192 + 512);
        const u16* b1 = bAddr(1);
        u16* d1 = pB1 + wvB;
        gld16(b1, d1);              gld16(b1 + sB8, d1 + 512);
        gld16(b1 + sBh, d1 + 8192); gld16(b1 + sBh + sB8, d1 + 8192 + 512);
    }
    const u16* aP = aAddr(1);
    const u16* bP = bAddr(2);
    asm volatile("s_waitcnt vmcnt(4)" ::: "memory");
    __builtin_amdgcn_s_barrier();
    FENCE();

    const int aoff0 = (wr * 128 + fr) * 64 + ((fq ^ (fr & 7)) << 3);
    const int aoff1 = (wr * 128 + fr) * 64 + (((4 + fq) ^ (fr & 7)) << 3);
    const int boff0 = (wcq * 64 + fr) * 64 + ((fq ^ (fr & 7)) << 3);
    const int boff1 = (wcq * 64 + fr) * 64 + (((4 + fq) ^ (fr & 7)) << 3);

    short8 af0[4][2], af1[4][2], bf0[2][2], bf1[2][2];

#define READ_AQ(DEST, MQ)                                                      \
    _Pragma("unroll")                                                          \
    for (int mi = 0; mi < 4; ++mi) {                                           \
        DEST[mi][0] = *(const short8*)&Ab[aoff0 + ((MQ) * 64 + mi * 16) * 64]; \
        DEST[mi][1] = *(const short8*)&Ab[aoff1 + ((MQ) * 64 + mi * 16) * 64]; \
    }
#define READ_BQ(BF, NQ)                                                        \
    _Pragma("unroll")                                                          \
    for (int ni = 0; ni < 2; ++ni) {                                           \
        BF[ni][0] = *(const short8*)&Bb[boff0 + ((NQ) * 32 + ni * 16) * 64];   \
        BF[ni][1] = *(const short8*)&Bb[boff1 + ((NQ) * 32 + ni * 16) * 64];   \
    }
#define MFMA_Q2(MQ, NQ, AF, BF)                                                \
    __builtin_amdgcn_s_setprio(1);                                             \
    _Pragma("unroll")                                                          \
    for (int mi = 0; mi < 4; ++mi) {                                           \
        _Pragma("unroll")                                                      \
        for (int ni = 0; ni < 2; ++ni) {                                       \
            _Pragma("unroll")                                                  \
            for (int kk = 0; kk < 2; ++kk)                                     \
                acc[(MQ) * 4 + mi][(NQ) * 2 + ni] =                            \
                    __builtin_amdgcn_mfma_f32_16x16x32_bf16(                   \
                        AF[mi][kk], BF[ni][kk],                                \
                        acc[(MQ) * 4 + mi][(NQ) * 2 + ni], 0, 0, 0);           \
        }                                                                      \
    }                                                                          \
    __builtin_amdgcn_s_setprio(0)

#define TILEBODY(BUF_, BRD_, BST_, DO_A_, DO_B_, STEPA_, STEPB_, VM_)          \
  {                                                                            \
    const u16* Ab = &As[BUF_][0];                                              \
    const u16* Bb = (BRD_);                                                    \
    u16* bDst = (BST_) + wvB;                                                  \
    READ_AQ(af0, 0);                                                           \
    READ_BQ(bf0, 0);                                                           \
    READ_BQ(bf1, 1);                                                           \
    if (DO_A_) { gld16(aP, uA + ((BUF_) ^ 1) * 16384);                         \
                 gld16(aP + sA8, uA + ((BUF_) ^ 1) * 16384 + 512); }           \
    MFMA_Q2(0, 0, af0, bf0);                                                   \
    READ_AQ(af1, 1);                                                           \
    if (DO_A_) { gld16(aP + sAh, uA + ((BUF_) ^ 1) * 16384 + 8192);            \
                 gld16(aP + sAh + sA8, uA + ((BUF_) ^ 1) * 16384 + 8192 + 512);\
                 aP += (STEPA_); }                                             \
    MFMA_Q2(0, 1, af0, bf1);                                                   \
    if (DO_B_) { gld16(bP, bDst);                                              \
                 gld16(bP + sB8, bDst + 512); }                                \
    MFMA_Q2(1, 1, af1, bf1);                                                   \
    if (DO_B_) { gld16(bP + sBh, bDst + 8192);                                 \
                 gld16(bP + sBh + sB8, bDst + 8192 + 512);                     \
                 bP += (STEPB_); }                                             \
    MFMA_Q2(1, 0, af1, bf0);                                                   \
    if ((VM_) == 4) asm volatile("s_waitcnt vmcnt(4)" ::: "memory");           \
    else if ((VM_) == 0) asm volatile("s_waitcnt vmcnt(0)" ::: "memory");      \
    SBAR();                                                                    \
  }

    int t = 0;
    for (; t + 3 < tot; t += 2) {
        const long long stA1 = (((t + 2) & kmask) != 0) ? 64 : dAtap;
        const long long stA2 = (((t + 3) & kmask) != 0) ? 64 : dAtap;
        const long long stB1 = (((t + 3) & kmask) != 0) ? 64 : dBtap;
        const long long stB2 = (((t + 4) & kmask) != 0) ? 64 : dBtap;
        TILEBODY(0, pB0, pB2, 1, 1, stA1, stB1, 4);
        TILEBODY(1, pB1, pB0, 1, 1, stA2, stB2, 4);
        u16* tmpB = pB0; pB0 = pB2; pB2 = pB1; pB1 = tmpB;
    }
    TILEBODY(0, pB0, pB2, 1, 0, 0, 0, 0);
    TILEBODY(1, pB1, pB0, 0, 0, 0, 0, -1);
#undef READ_AQ
#undef READ_BQ
#undef MFMA_Q2
#undef TILEBODY

    if constexpr (OUTK == 2) {
        const float* bias = p.bias + (long long)bz * p.bias_bstride;
#pragma unroll
        for (int m = 0; m < 8; ++m) {
#pragma unroll
            for (int n = 0; n < 4; ++n) {
                int col = c0 + wcq * 64 + n * 16 + fr;
                if (col >= p.store_ncols) continue;
                float cb = bias[col];
#pragma unroll
                for (int r = 0; r < 4; ++r) {
                    int row = n0 + wr * 128 + m * 16 + fq * 4 + r;
                    ((float*)p.out)[(long long)bz * p.o_bstride + (long long)col * p.ldc + row]
                        = acc[m][n][r] * p.scale + cb;
                }
            }
        }
        return;
    } else {
        const float* bias = p.bias ? p.bias + (long long)bz * p.bias_bstride : nullptr;
#pragma unroll
        for (int m = 0; m < 8; ++m) {
#pragma unroll
            for (int n = 0; n < 4; ++n) {
                int col = c0 + wcq * 64 + n * 16 + fr;
                float cb = (OUTK == 1 && bias) ? bias[col] : 0.f;
#pragma unroll
                for (int r = 0; r < 4; ++r) {
                    int row = n0 + wr * 128 + m * 16 + fq * 4 + r;
                    float v = acc[m][n][r] * p.scale + cb;
                    if (OUTK == 5) v += bias[row];
                    ((u16*)p.out)[(long long)bz * p.o_bstride + (long long)row * p.ldc + col]
                        = f2bf(v);
                }
            }
        }
    }
}

// =============== GLU GEMM: 256x128 tile, BK=32, tri-buffered A+B, 2 blocks/CU ===============
// 8 waves in 4M x 2N grid; wave tile 64x64 (acc 4x4). LDS = 3*16K + 3*8K = 72 KiB.
// 1 barrier per K-tile; stage tile t+2 each tile; vmcnt(3) counted wait.
// Swizzle (r15 fix): slot = base ^ (row&3) ^ ((row>>2)&3) — rows {0,4,8,12} now hit
// distinct slots; residual aliasing is 2-way (free, m136). Same involution on the
// staging source and the fragment reads (rule 21).
__global__ __launch_bounds__(512, 4)
void gemm128glu(GemmP p, int tilesM, int tilesN) {
    __shared__ __align__(16) u16 As[3][256 * 32];
    __shared__ __align__(16) u16 Bs[3][128 * 32];
    const int tid = threadIdx.x;
    const int lane = tid & 63;
    const int wv = tid >> 6;
    const int wr4 = wv >> 1, wc2 = wv & 1;         // 4M x 2N wave grid
    const int fr = lane & 15, fq = lane >> 4;

    const int nwg = gridDim.x;
    int widx = (blockIdx.x & 7) * (nwg >> 3) + (blockIdx.x >> 3);
    const int mt = widx % tilesM; widx /= tilesM;
    const int nt = widx % tilesN;
    const int bz = widx / tilesN;
    const int n0 = mt * 256, c0 = nt * 128;

    const int lda = p.lda, ldb = p.ldb;
    const u16* Abase = p.A + (long long)bz * p.a_bstride;
    const u16* Bbase = p.Bw;                        // b_bstride == 0 for GLU weights
    const int kmask = (1 << p.ks_log2) - 1;         // ks_log2 = 4 (BK=32, K=512)
    const int tot = p.ntaps << p.ks_log2;           // 80

    f32x4 acc[4][4];
#pragma unroll
    for (int m = 0; m < 4; ++m)
#pragma unroll
        for (int n = 0; n < 4; ++n) acc[m][n] = (f32x4){0.f, 0.f, 0.f, 0.f};

    // staging geometry: 4 16B-slots per 32-elem row; swizzle slot ^ (row&3) ^ ((row>>2)&3)
    const int srow = lane >> 2, sslot = lane & 3;
    const int js = (sslot ^ (srow & 3) ^ ((srow >> 2) & 3)) << 3;
    const int sr0 = wv * 16 + srow;                 // A pass1 rows 0..127 (pass2 +128); B rows 0..127
    const long long sAh = 128LL * lda;
    const long long dAtap = (long long)p.dshift * lda - (long long)kmask * 32;
    const long long dBtap = p.b_tapstride - (long long)kmask * 32;

    auto aAddr = [&](int t) -> const u16* {
        int tap = t >> p.ks_log2;
        return Abase + (long long)(n0 + p.shift0 + tap * p.dshift + sr0) * lda
               + ((t & kmask) << 5) + js;
    };
    auto bAddr = [&](int t) -> const u16* {
        int tap = t >> p.ks_log2;
        return Bbase + (long long)tap * p.b_tapstride
               + (long long)(c0 + sr0) * ldb + ((t & kmask) << 5) + js;
    };

    const int wv512 = wv * 512;                    // wave-uniform LDS staging base (u16)
    u16* pA0 = &As[0][0]; u16* pA1 = &As[1][0]; u16* pA2 = &As[2][0];
    u16* pB0 = &Bs[0][0]; u16* pB1 = &Bs[1][0]; u16* pB2 = &Bs[2][0];

    // ---- prologue: tiles 0,1 fully staged ----
    {
        const u16* a0 = aAddr(0);
        gld16(a0, pA0 + wv512); gld16(a0 + sAh, pA0 + wv512 + 4096);
        const u16* b0 = bAddr(0);
        gld16(b0, pB0 + wv512);
        const u16* a1 = aAddr(1);
        gld16(a1, pA1 + wv512); gld16(a1 + sAh, pA1 + wv512 + 4096);
        const u16* b1 = bAddr(1);
        gld16(b1, pB1 + wv512);
    }
    const u16* aP = aAddr(2);
    const u16* bP = bAddr(2);
    asm volatile("s_waitcnt vmcnt(0)" ::: "memory");
    __builtin_amdgcn_s_barrier();
    FENCE();

    // fragment-read offsets (u16 units): row stride 32, slot = fq ^ (fr&3) ^ ((fr>>2)&3)
    const int aoffb = (wr4 * 64 + fr) * 32 + ((fq ^ (fr & 3) ^ ((fr >> 2) & 3)) << 3);
    const int boffb = (wc2 * 64 + fr) * 32 + ((fq ^ (fr & 3) ^ ((fr >> 2) & 3)) << 3);

#define T128BODY(T_, DO_, VM_)                                                 \
  {                                                                            \
    const u16* Ab = pA0;                                                       \
    const u16* Bb = pB0;                                                       \
    short8 af[4], bf[4];                                                       \
    _Pragma("unroll")                                                          \
    for (int mi = 0; mi < 4; ++mi) af[mi] = *(const short8*)&Ab[aoffb + mi * 512]; \
    _Pragma("unroll")                                                          \
    for (int ni = 0; ni < 4; ++ni) bf[ni] = *(const short8*)&Bb[boffb + ni * 512]; \
    if (DO_) {                                                                 \
        gld16(aP, pA2 + wv512);                                                \
        gld16(aP + sAh, pA2 + wv512 + 4096);                                   \
        gld16(bP, pB2 + wv512);                                                \
        long long stA = ((((T_) + 3) & kmask) != 0) ? 32 : dAtap;              \
        long long stB = ((((T_) + 3) & kmask) != 0) ? 32 : dBtap;              \
        aP += stA; bP += stB;                                                  \
    }                                                                          \
    __builtin_amdgcn_s_setprio(1);                                             \
    _Pragma("unroll")                                                          \
    for (int mi = 0; mi < 4; ++mi)                                             \
        _Pragma("unroll")                                                      \
        for (int ni = 0; ni < 4; ++ni)                                         \
            acc[mi][ni] = __builtin_amdgcn_mfma_f32_16x16x32_bf16(             \
                af[mi], bf[ni], acc[mi][ni], 0, 0, 0);                         \
    __builtin_amdgcn_s_setprio(0);                                             \
    if ((VM_) == 3) asm volatile("s_waitcnt vmcnt(3)" ::: "memory");           \
    else if ((VM_) == 0) asm volatile("s_waitcnt vmcnt(0)" ::: "memory");      \
    SBAR();                                                                    \
    u16* tA = pA0; pA0 = pA1; pA1 = pA2; pA2 = tA;                             \
    u16* tB = pB0; pB0 = pB1; pB1 = pB2; pB2 = tB;                             \
  }

    int t = 0;
    for (; t < tot - 2; ++t) T128BODY(t, 1, 3);
    T128BODY(t, 0, 0);
    T128BODY(t, 0, -1);
#undef T128BODY

    // ---- GLU epilogue: n={0,2} "a", n={1,3} gate; residual h_in via A operand ----
    const float* bp = p.bias;
#pragma unroll
    for (int m = 0; m < 4; ++m) {
#pragma unroll
        for (int pr = 0; pr < 2; ++pr) {
            int ca = c0 + wc2 * 64 + (2 * pr) * 16 + fr;
            int chan = (c0 >> 1) + wc2 * 32 + pr * 16 + fr;
            float biasa = bp[ca], biasb = bp[ca + 16];
#pragma unroll
            for (int r = 0; r < 4; ++r) {
                int row = n0 + wr4 * 64 + m * 16 + fq * 4 + r;
                float a = acc[m][2 * pr][r] + biasa;
                float bq = acc[m][2 * pr + 1][r] + biasb;
                float sig = 1.f / (1.f + __expf(-bq));
                float h = bf2f(Abase[(long long)row * lda + chan]);
                ((u16*)p.out)[(long long)bz * p.o_bstride + (long long)row * p.ldc + chan]
                    = f2bf((h + a * sig) * SQRT_HALF_F);
            }
        }
    }
}

// ---------------- elementwise / helper kernels ----------------

// Source-coalesced GLU weight convert+permute (inverse of the 128-tile glu_perm).
__global__ void cvt_glu(const float* src, u16* dst) {
    int u = blockIdx.x * 256 + threadIdx.x;          // 8*1024*512
    if (u >= 8 * 1024 * 512) return;
    int i = u & 511;
    int o = (u >> 9) & 1023;
    int l = u >> 19;
    // g = glu_perm^{-1}(o)
    int hi = o >> 9;
    int op = o & 511;
    int tile = op >> 6;
    int wc2i = (op >> 5) & 1;
    int nhalf = (op >> 4) & 1;
    int fr = op & 15;
    int g = tile * 128 + wc2i * 64 + (2 * nhalf + hi) * 16 + fr;
    const float* s = src + (long long)u * 5;
    long long dbase = ((long long)l * 5 * 1024 + g) * 512 + i;
#pragma unroll
    for (int k = 0; k < 5; ++k)
        dst[dbase + (long long)k * 1024 * 512] = f2bf(s[k]);
}

__global__ void perm_bias(const float* gb, float* biasP) {
    int t = blockIdx.x * 256 + threadIdx.x;
    if (t >= 8 * 1024) return;
    int g = t & 1023, l = t >> 10;
    biasP[t] = gb[l * 1024 + glu_perm(g)];
}

__global__ void cvt_all(const float* enc_start_w, const float* enc_end_w,
                        const float* w_pre, const float* w_post,
                        u16* wstart, u16* wend, u16* wpre, u16* wpost) {
    int t = blockIdx.x * 256 + threadIdx.x;
    if (t < 131072) {
        int i = t & 255, o = t >> 8;
        wstart[t] = f2bf(i < 240 ? enc_start_w[o * 240 + i] : 0.f);
    } else if (t < 655360) {
        int q = t - 131072;
        wend[q] = f2bf(enc_end_w[q]);
    } else if (t < 786432) {
        int q = t - 655360;
        int i = q & 255, o = q >> 8;
        wpre[q] = f2bf(i < 240 ? w_pre[o * 240 + i] : 0.f);
    } else if (t < 1048576) {
        int q = t - 786432;
        int i = q & 1023, o = q >> 10;
        wpost[q] = f2bf(o < 240 ? w_post[o * 1024 + i] : 0.f);
    }
}

__global__ void transpose_in(const float* in_s, const float* in_t, u16* XS, u16* XT) {
    __shared__ float tile[32][33];
    int zz = blockIdx.z;
    const float* src = (zz < BB) ? in_s : in_t;
    u16* dst = (zz < BB) ? XS : XT;
    int b = zz & (BB - 1);
    int n0 = blockIdx.x * 32, c0 = blockIdx.y * 32;
    int tx = threadIdx.x, ty = threadIdx.y;
    int c = c0 + ty, n = n0 + tx;
    float v = 0.f;
    if (c < 240) v = src[((long long)b * 240 + c) * 2048 + n];
    tile[ty][tx] = v;
    __syncthreads();
    dst[((long long)b * 2048 + (n0 + ty)) * 256 + (c0 + tx)] = f2bf(tile[tx][ty]);
}

__global__ void zero_pads(u16* h0, u16* h1) {
    long long t = (long long)blockIdx.x * blockDim.x + threadIdx.x;
    const long long half = (long long)BB * 128 * 512;
    if (t >= 2 * half) return;
    u16* h = (t < half) ? h0 : h1;
    long long q = (t < half) ? t : t - half;
    int c = (int)(q % 512); long long r = q / 512;
    int rr = (int)(r % 128); int b = (int)(r / 128);
    int row = rr < HPAD ? rr : (HROWS - 128 + rr);
    h[((long long)b * HROWS + row) * 512 + c] = 0;
}

__global__ void bias_kernel(const float* ct,
                            const float* wcpre, const float* wpre_f, const float* bpre,
                            const float* wcpost, const float* wpost_f, const float* bpost,
                            float* qbias, float* ybias) {
    __shared__ float s[1024];
    int b = blockIdx.x; int tid = threadIdx.x;
    if (blockIdx.y == 0) {
        if (tid < 240) {
            float a = 0.f;
            for (int c = 0; c < 8; ++c) a += ct[b * 8 + c] * wcpre[c * 240 + tid];
            s[tid] = a;
        }
        __syncthreads();
        for (int o = tid; o < 512; o += 256) {
            float a = bpre[o];
            for (int d0 = 0; d0 < 240; ++d0) a += wpre_f[o * 240 + d0] * s[d0];
            qbias[b * 512 + o] = a;
        }
    } else {
        for (int e = tid; e < 1024; e += 256) {
            float a = 0.f;
            for (int c = 0; c < 8; ++c) a += ct[b * 8 + c] * wcpost[c * 1024 + e];
            s[e] = a;
        }
        __syncthreads();
        if (tid < 240) {
            float a = bpost[tid];
            for (int e = 0; e < 1024; ++e) a += wpost_f[tid * 1024 + e] * s[e];
            ybias[b * 240 + tid] = a;
        }
    }
}

__global__ __launch_bounds__(256)
void softmax_rows(const u16* St, u16* AT) {
    int b = blockIdx.y;
    int t = blockIdx.x * 4 + (threadIdx.x >> 6);
    int lane = threadIdx.x & 63;
    const u16* row = St + ((long long)b * TT + t) * NN;
    short8 v[4];
#pragma unroll
    for (int i = 0; i < 4; ++i) v[i] = ((const short8*)row)[i * 64 + lane];
    float f[32];
#pragma unroll
    for (int i = 0; i < 4; ++i)
#pragma unroll
        for (int j = 0; j < 8; ++j) f[i * 8 + j] = bf2f((u16)v[i][j]);
    float m = -3.4e38f;
#pragma unroll
    for (int i = 0; i < 32; ++i) m = fmaxf(m, f[i]);
#pragma unroll
    for (int s = 1; s < 64; s <<= 1) m = fmaxf(m, __shfl_xor(m, s, 64));
    float sum = 0.f;
#pragma unroll
    for (int i = 0; i < 32; ++i) { f[i] = __expf(f[i] - m); sum += f[i]; }
#pragma unroll
    for (int s = 1; s < 64; s <<= 1) sum += __shfl_xor(sum, s, 64);
    float li = 1.f / sum;
    u16* atrow = AT + ((long long)b * TT + t) * NN;
#pragma unroll
    for (int i = 0; i < 4; ++i) {
        short8 pk;
#pragma unroll
        for (int j = 0; j < 8; ++j) pk[j] = (short)f2bf(f[i * 8 + j] * li);
        ((short8*)atrow)[i * 64 + lane] = pk;
    }
}

__global__ void transpose_out(const u16* AT, float* A) {
    __shared__ float tile[32][33];
    int b = blockIdx.z;
    int n0 = blockIdx.x * 32, t0 = blockIdx.y * 32;
    int tx = threadIdx.x, ty = threadIdx.y;
#pragma unroll
    for (int k = 0; k < 4; ++k) {
        int t = t0 + ty + k * 8;
        tile[ty + k * 8][tx] = bf2f(AT[((long long)b * TT + t) * NN + n0 + tx]);
    }
    __syncthreads();
#pragma unroll
    for (int k = 0; k < 4; ++k) {
        int n = n0 + ty + k * 8;
        A[((long long)b * NN + n) * TT + t0 + tx] = tile[tx][ty + k * 8];
    }
}

// ---------------- host orchestration ----------------

extern "C" void kernel_launch(void* const* d_in, const int* in_sizes, int n_in,
                              void* d_out, int out_size, void* d_ws, size_t ws_size,
                              hipStream_t stream) {
    const float* in_s        = (const float*)d_in[0];
    const float* in_t        = (const float*)d_in[1];
    const float* c_t         = (const float*)d_in[2];
    const float* enc_start_w = (const float*)d_in[3];
    const float* enc_start_b = (const float*)d_in[4];
    const float* glu_w       = (const float*)d_in[5];
    const float* glu_b       = (const float*)d_in[6];
    const float* enc_end_w   = (const float*)d_in[7];
    const float* enc_end_b   = (const float*)d_in[8];
    const float* wc_pre      = (const float*)d_in[9];
    const float* w_pre       = (const float*)d_in[10];
    const float* b_pre       = (const float*)d_in[11];
    const float* wc_post     = (const float*)d_in[12];
    const float* w_post      = (const float*)d_in[13];
    const float* b_post      = (const float*)d_in[14];

    // workspace layout
    char* w = (char*)d_ws;
    u16* wglu   = (u16*)w; w += 8LL * 5 * 1024 * 512 * 2;
    u16* wstart = (u16*)w; w += 512LL * 256 * 2;
    u16* wend   = (u16*)w; w += 1024LL * 512 * 2;
    u16* wpre   = (u16*)w; w += 512LL * 256 * 2;
    u16* wpost  = (u16*)w; w += 256LL * 1024 * 2;
    u16* XS     = (u16*)w; w += (long long)BB * NN * 256 * 2;
    u16* XT     = (u16*)w; w += (long long)BB * TT * 256 * 2;
    u16* h0     = (u16*)w; w += (long long)BB * HROWS * 512 * 2;
    u16* h1     = (u16*)w; w += (long long)BB * HROWS * 512 * 2;
    u16* Kb     = (u16*)w; w += (long long)BB * NN * 512 * 2;
    u16* Vb     = (u16*)w; w += (long long)BB * 512 * NN * 2;
    u16* Rc     = (u16*)w; w += (long long)BB * TT * 1024 * 2;
    u16* ATb    = (u16*)w; w += (long long)BB * TT * NN * 2;
    float* qbias = (float*)w; w += 16LL * 512 * 4;
    float* ybias = (float*)w; w += 16LL * 256 * 4;
    float* biasP = (float*)w; w += 8LL * 1024 * 4;
    if ((size_t)(w - (char*)d_ws) > ws_size) return;

    float* yout = (float*)d_out;
    float* Areg = yout + Y_SIZE;
    u16* Sbf = (u16*)Areg;

    // ---- conversions / setup ----
    cvt_glu<<<(8 * 1024 * 512) / 256, 256, 0, stream>>>(glu_w, wglu);
    perm_bias<<<(8 * 1024 + 255) / 256, 256, 0, stream>>>(glu_b, biasP);
    cvt_all<<<1048576 / 256, 256, 0, stream>>>(enc_start_w, enc_end_w, w_pre, w_post,
                                               wstart, wend, wpre, wpost);
    transpose_in<<<dim3(NN / 32, 256 / 32, 2 * BB), dim3(32, 32), 0, stream>>>(in_s, in_t, XS, XT);
    zero_pads<<<(2LL * BB * 128 * 512 + 255) / 256, 256, 0, stream>>>(h0, h1);
    bias_kernel<<<dim3(16, 2), 256, 0, stream>>>(c_t, wc_pre, w_pre, b_pre,
                                                 wc_post, w_post, b_post, qbias, ybias);

    // ---- enc_start ----
    {
        GemmP p{}; p.A = XS; p.a_bstride = (long long)NN * 256; p.lda = 256;
        p.Bw = wstart; p.b_bstride = 0; p.b_tapstride = 0; p.ldb = 256;
        p.ntaps = 1; p.shift0 = 0; p.dshift = 0; p.Kt = 256; p.ks_log2 = 2;
        p.out = h0 + HPAD * 512; p.o_bstride = (long long)HROWS * 512; p.ldc = 512;
        p.bias = enc_start_b; p.bias_bstride = 0; p.scale = 1.f; p.store_ncols = 512;
        gemm256<1><<<8 * 2 * 16, 512, 0, stream>>>(p, 8, 2);
    }

    // ---- 8 GLU blocks: 256x128/BK=32 kernel, 2 blocks/CU, conflict-free swizzle ----
    const int dils[8] = {1, 3, 9, 27, 1, 3, 9, 27};
    u16* hin = h0; u16* hout = h1;
    for (int l = 0; l < 8; ++l) {
        GemmP q{}; q.A = hin + HPAD * 512; q.a_bstride = (long long)HROWS * 512; q.lda = 512;
        q.Bw = wglu + (long long)l * 5 * 1024 * 512; q.b_bstride = 0;
        q.b_tapstride = 1024LL * 512; q.ldb = 512;
        q.ntaps = 5; q.shift0 = -2 * dils[l]; q.dshift = dils[l]; q.Kt = 512; q.ks_log2 = 4;
        q.out = hout + HPAD * 512; q.o_bstride = (long long)HROWS * 512; q.ldc = 512;
        q.bias = biasP + l * 1024; q.bias_bstride = 0; q.scale = 1.f; q.store_ncols = 1024;
        gemm128glu<<<8 * 8 * 16, 512, 0, stream>>>(q, 8, 8);
        u16* tmp = hin; hin = hout; hout = tmp;
    }

    // ---- enc_end K ----
    {
        GemmP p{}; p.A = hin + HPAD * 512; p.a_bstride = (long long)HROWS * 512; p.lda = 512;
        p.Bw = wend; p.b_bstride = 0; p.b_tapstride = 0; p.ldb = 512;
        p.ntaps = 1; p.shift0 = 0; p.dshift = 0; p.Kt = 512; p.ks_log2 = 3;
        p.out = Kb; p.o_bstride = (long long)NN * 512; p.ldc = 512;
        p.bias = enc_end_b; p.bias_bstride = 0; p.scale = 1.f; p.store_ncols = 512;
        gemm256<1><<<8 * 2 * 16, 512, 0, stream>>>(p, 8, 2);
    }
    // ---- enc_end V (operand-swapped, row-bias) ----
    {
        GemmP p{}; p.A = wend + 512LL * 512; p.a_bstride = 0; p.lda = 512;
        p.Bw = hin + HPAD * 512; p.b_bstride = (long long)HROWS * 512; p.b_tapstride = 0; p.ldb = 512;
        p.ntaps = 1; p.shift0 = 0; p.dshift = 0; p.Kt = 512; p.ks_log2 = 3;
        p.out = Vb; p.o_bstride = 512LL * NN; p.ldc = NN;
        p.bias = enc_end_b + 512; p.bias_bstride = 0; p.scale = 1.f; p.store_ncols = NN;
        gemm256<5><<<2 * 8 * 16, 512, 0, stream>>>(p, 2, 8);
    }

    // ---- pre-decoder Q ----
    {
        GemmP p{}; p.A = XT; p.a_bstride = (long long)TT * 256; p.lda = 256;
        p.Bw = wpre; p.b_bstride = 0; p.b_tapstride = 0; p.ldb = 256;
        p.ntaps = 1; p.shift0 = 0; p.dshift = 0; p.Kt = 256; p.ks_log2 = 2;
        p.out = Rc + 512; p.o_bstride = (long long)TT * 1024; p.ldc = 1024;
        p.bias = qbias; p.bias_bstride = 512; p.scale = 1.f; p.store_ncols = 512;
        gemm256<1><<<8 * 2 * 16, 512, 0, stream>>>(p, 8, 2);
    }

    // ---- scores ----
    {
        GemmP p{}; p.A = Rc + 512; p.a_bstride = (long long)TT * 1024; p.lda = 1024;
        p.Bw = Kb; p.b_bstride = (long long)NN * 512; p.b_tapstride = 0; p.ldb = 512;
        p.ntaps = 1; p.shift0 = 0; p.dshift = 0; p.Kt = 512; p.ks_log2 = 3;
        p.out = Sbf; p.o_bstride = (long long)TT * NN; p.ldc = NN;
        p.bias = nullptr; p.bias_bstride = 0; p.scale = 0.04419417382415922f;
        p.store_ncols = NN;
        gemm256<1><<<8 * 8 * 16, 512, 0, stream>>>(p, 8, 8);
    }

    // ---- softmax + transpose ----
    softmax_rows<<<dim3(TT / 4, BB), 256, 0, stream>>>(Sbf, ATb);
    transpose_out<<<dim3(NN / 32, TT / 32, BB), dim3(32, 8), 0, stream>>>(ATb, Areg);

    // ---- R = V x A ----
    {
        GemmP p{}; p.A = ATb; p.a_bstride = (long long)TT * NN; p.lda = NN;
        p.Bw = Vb; p.b_bstride = 512LL * NN; p.b_tapstride = 0; p.ldb = NN;
        p.ntaps = 1; p.shift0 = 0; p.dshift = 0; p.Kt = NN; p.ks_log2 = 5;
        p.out = Rc; p.o_bstride = (long long)TT * 1024; p.ldc = 1024;
        p.bias = nullptr; p.bias_bstride = 0; p.scale = 1.f; p.store_ncols = 512;
        gemm256<1><<<8 * 2 * 16, 512, 0, stream>>>(p, 8, 2);
    }

    // ---- post-decoder ----
    {
        GemmP p{}; p.A = Rc; p.a_bstride = (long long)TT * 1024; p.lda = 1024;
        p.Bw = wpost; p.b_bstride = 0; p.b_tapstride = 0; p.ldb = 1024;
        p.ntaps = 1; p.shift0 = 0; p.dshift = 0; p.Kt = 1024; p.ks_log2 = 4;
        p.out = yout; p.o_bstride = (long long)DIN * TT; p.ldc = TT;
        p.bias = ybias; p.bias_bstride = 240; p.scale = 1.f; p.store_ncols = 240;
        gemm256<2><<<8 * 1 * 16, 512, 0, stream>>>(p, 8, 1);
    }
}

// Round 16
// 1635.786 us; speedup vs baseline: 1.1114x; 1.1114x over previous
//
#include <hip/hip_runtime.h>
#include <cstdint>
#include <cstddef>

typedef unsigned short u16;
typedef __attribute__((ext_vector_type(8))) short short8;
typedef __attribute__((ext_vector_type(4))) float f32x4;

static constexpr int BB = 16, DIN = 240, NN = 2048, TT = 2048;
static constexpr long long Y_SIZE = (long long)BB * DIN * TT;          // 7,864,320 f32
static constexpr float SQRT_HALF_F = 0.70710678118654752440f;
static constexpr int HPAD = 64;                 // zero-pad rows each side of h (max shift 54)
static constexpr int HROWS = NN + 2 * HPAD;     // 2176

#define DEVI __device__ __forceinline__

DEVI u16 f2bf(float f) {
    unsigned u = __builtin_bit_cast(unsigned, f);
    u += 0x7FFFu + ((u >> 16) & 1u);
    return (u16)(u >> 16);
}
DEVI float bf2f(u16 h) {
    unsigned u = ((unsigned)h) << 16;
    return __builtin_bit_cast(float, u);
}

DEVI void gld16(const void* g, const void* l) {
    __builtin_amdgcn_global_load_lds(
        (const __attribute__((address_space(1))) unsigned int*)g,
        (__attribute__((address_space(3))) unsigned int*)l, 16, 0, 0);
}

// GLU column permutation for the 256-wide tile geometry: GEMM col g -> conv output
// channel. Within each wave's 64-col span, fragments n={0,2} are "a" channels and
// n={1,3} the matching gate "b" channels at +16 GEMM cols.
DEVI int glu_perm(int g) {
    int tile = g >> 8, r = g & 255;
    int wcq = r >> 6, r2 = r & 63;
    int n = r2 >> 4, fr = r2 & 15;
    return tile * 128 + wcq * 32 + (n >> 1) * 16 + fr + (n & 1) * 512;
}

// ---------------- GEMM params ----------------
// C[row][col] = scale * sum_taps sum_k A[row+shift][k] * B[col][k]  (+bias)
struct GemmP {
    const u16* A; long long a_bstride; int lda;
    const u16* Bw; long long b_bstride; long long b_tapstride; int ldb;
    int ntaps; int shift0; int dshift; int Kt; int ks_log2;
    void* out; long long o_bstride; int ldc;
    const float* bias; int bias_bstride;
    float scale;
    int store_ncols;
};

#define FENCE() asm volatile("" ::: "memory")
#define SBAR()  do { FENCE(); __builtin_amdgcn_s_barrier(); FENCE(); } while (0)

// =============== 256x256 MFMA GEMM, 1-barrier K-tile, triple-buffered B ===============
// OUTK: 1 = bf16 row-major col-bias (+scale). 2 = f32 transposed col-bias, col-masked.
//       4 = GLU fused epilogue. 5 = bf16 row-bias.
// Requires tot (= ntaps << ks_log2) EVEN and >= 4.
//
// Hazard audit (1 barrier per K-tile; A double-buffered, B TRIPLE-buffered):
//  - All tile-t LDS reads are value-consumed by tile-t MFMAs (program order before
//    the barrier); data dependency forces lgkm completion, so no wave's reads of a
//    buffer extend past its tile-t barrier.
//  - A(t+1) staging writes As[(t+1)&1]; last readers (tile t-1) finished before
//    barrier(t-1), which precedes any tile-t staging. OK.
//  - B(t+2) staging writes B[(t+2)%3], distinct from B[t%3] (being read now) and
//    B[(t+1)%3] (read next); its last readers were tile t-1. OK.
//  - Arrival: vmcnt(4) at tile-t end leaves only B(t+2)'s 4 loads outstanding ->
//    A(t+1) (issued earlier in tile t) and B(t+1) (issued in tile t-1) landed
//    before barrier(t) releases tile t+1's reads. OK.
template <int OUTK>
__global__ __launch_bounds__(512, 2)
void gemm256(GemmP p, int tilesM, int tilesN) {
    __shared__ __align__(16) u16 As[2][256 * 64];
    __shared__ __align__(16) u16 Bs[3][256 * 64];   // 64K + 96K = 160 KiB exactly
    const int tid = threadIdx.x;
    const int lane = tid & 63;
    const int wv = tid >> 6;
    const int wr = wv >> 2, wcq = wv & 3;          // 2M x 4N wave grid
    const int fr = lane & 15, fq = lane >> 4;

    const int nwg = gridDim.x;
    int widx = (blockIdx.x & 7) * (nwg >> 3) + (blockIdx.x >> 3);
    const int mt = widx % tilesM; widx /= tilesM;
    const int nt = widx % tilesN;
    const int bz = widx / tilesN;
    const int n0 = mt * 256, c0 = nt * 256;

    const int lda = p.lda, ldb = p.ldb;
    const u16* Abase = p.A + (long long)bz * p.a_bstride;
    const u16* Bbase = p.Bw + (long long)bz * p.b_bstride;
    const int kmask = (1 << p.ks_log2) - 1;
    const int tot = p.ntaps << p.ks_log2;

    f32x4 acc[8][4];
#pragma unroll
    for (int m = 0; m < 8; ++m)
#pragma unroll
        for (int n = 0; n < 4; ++n) acc[m][n] = (f32x4){0.f, 0.f, 0.f, 0.f};

    const int srow = lane >> 3, sslot = lane & 7;
    const int js = (sslot ^ srow) << 3;
    const int sr0 = wv * 16 + srow;
    const int wvB = wv * 1024;

    const long long sA8 = 8LL * lda, sAh = 128LL * lda;
    const long long sB8 = 8LL * ldb, sBh = 128LL * ldb;
    const long long dAtap = (long long)p.dshift * lda - (long long)kmask * 64;
    const long long dBtap = p.b_tapstride - (long long)kmask * 64;

    auto aAddr = [&](int t) -> const u16* {
        int tap = t >> p.ks_log2;
        return Abase + (long long)(n0 + p.shift0 + tap * p.dshift + sr0) * lda
               + ((t & kmask) << 6) + js;
    };
    auto bAddr = [&](int t) -> const u16* {
        int tap = t >> p.ks_log2;
        return Bbase + (long long)tap * p.b_tapstride
               + (long long)(c0 + sr0) * ldb + ((t & kmask) << 6) + js;
    };

    u16* uA = &As[0][wvB];
    u16* pB0 = &Bs[0][0];
    u16* pB1 = &Bs[1][0];
    u16* pB2 = &Bs[2][0];

    {
        const u16* a0 = aAddr(0);
        gld16(a0, uA);              gld16(a0 + sA8, uA + 512);
        gld16(a0 + sAh, uA + 8192); gld16(a0 + sAh + sA8, uA + 8192 + 512);
        const u16* b0 = bAddr(0);
        u16* d0 = pB0 + wvB;
        gld16(b0, d0);              gld16(b0 + sB8, d0 + 512);
        gld16(b0 + sBh, d0 + 8192); gld16(b0 + sBh + sB8, d0 + 8192 + 512);
        const u16* b1 = bAddr(1);
        u16* d1 = pB1 + wvB;
        gld16(b1, d1);              gld16(b1 + sB8, d1 + 512);
        gld16(b1 + sBh, d1 + 8192); gld16(b1 + sBh + sB8, d1 + 8192 + 512);
    }
    const u16* aP = aAddr(1);
    const u16* bP = bAddr(2);
    asm volatile("s_waitcnt vmcnt(4)" ::: "memory");
    __builtin_amdgcn_s_barrier();
    FENCE();

    const int aoff0 = (wr * 128 + fr) * 64 + ((fq ^ (fr & 7)) << 3);
    const int aoff1 = (wr * 128 + fr) * 64 + (((4 + fq) ^ (fr & 7)) << 3);
    const int boff0 = (wcq * 64 + fr) * 64 + ((fq ^ (fr & 7)) << 3);
    const int boff1 = (wcq * 64 + fr) * 64 + (((4 + fq) ^ (fr & 7)) << 3);

    short8 af0[4][2], af1[4][2], bf0[2][2], bf1[2][2];

#define READ_AQ(DEST, MQ)                                                      \
    _Pragma("unroll")                                                          \
    for (int mi = 0; mi < 4; ++mi) {                                           \
        DEST[mi][0] = *(const short8*)&Ab[aoff0 + ((MQ) * 64 + mi * 16) * 64]; \
        DEST[mi][1] = *(const short8*)&Ab[aoff1 + ((MQ) * 64 + mi * 16) * 64]; \
    }
#define READ_BQ(BF, NQ)                                                        \
    _Pragma("unroll")                                                          \
    for (int ni = 0; ni < 2; ++ni) {                                           \
        BF[ni][0] = *(const short8*)&Bb[boff0 + ((NQ) * 32 + ni * 16) * 64];   \
        BF[ni][1] = *(const short8*)&Bb[boff1 + ((NQ) * 32 + ni * 16) * 64];   \
    }
#define MFMA_Q2(MQ, NQ, AF, BF)                                                \
    __builtin_amdgcn_s_setprio(1);                                             \
    _Pragma("unroll")                                                          \
    for (int mi = 0; mi < 4; ++mi) {                                           \
        _Pragma("unroll")                                                      \
        for (int ni = 0; ni < 2; ++ni) {                                       \
            _Pragma("unroll")                                                  \
            for (int kk = 0; kk < 2; ++kk)                                     \
                acc[(MQ) * 4 + mi][(NQ) * 2 + ni] =                            \
                    __builtin_amdgcn_mfma_f32_16x16x32_bf16(                   \
                        AF[mi][kk], BF[ni][kk],                                \
                        acc[(MQ) * 4 + mi][(NQ) * 2 + ni], 0, 0, 0);           \
        }                                                                      \
    }                                                                          \
    __builtin_amdgcn_s_setprio(0)

#define TILEBODY(BUF_, BRD_, BST_, DO_A_, DO_B_, STEPA_, STEPB_, VM_)          \
  {                                                                            \
    const u16* Ab = &As[BUF_][0];                                              \
    const u16* Bb = (BRD_);                                                    \
    u16* bDst = (BST_) + wvB;                                                  \
    READ_AQ(af0, 0);                                                           \
    READ_BQ(bf0, 0);                                                           \
    READ_BQ(bf1, 1);                                                           \
    if (DO_A_) { gld16(aP, uA + ((BUF_) ^ 1) * 16384);                         \
                 gld16(aP + sA8, uA + ((BUF_) ^ 1) * 16384 + 512); }           \
    MFMA_Q2(0, 0, af0, bf0);                                                   \
    READ_AQ(af1, 1);                                                           \
    if (DO_A_) { gld16(aP + sAh, uA + ((BUF_) ^ 1) * 16384 + 8192);            \
                 gld16(aP + sAh + sA8, uA + ((BUF_) ^ 1) * 16384 + 8192 + 512);\
                 aP += (STEPA_); }                                             \
    MFMA_Q2(0, 1, af0, bf1);                                                   \
    if (DO_B_) { gld16(bP, bDst);                                              \
                 gld16(bP + sB8, bDst + 512); }                                \
    MFMA_Q2(1, 1, af1, bf1);                                                   \
    if (DO_B_) { gld16(bP + sBh, bDst + 8192);                                 \
                 gld16(bP + sBh + sB8, bDst + 8192 + 512);                     \
                 bP += (STEPB_); }                                             \
    MFMA_Q2(1, 0, af1, bf0);                                                   \
    if ((VM_) == 4) asm volatile("s_waitcnt vmcnt(4)" ::: "memory");           \
    else if ((VM_) == 0) asm volatile("s_waitcnt vmcnt(0)" ::: "memory");      \
    SBAR();                                                                    \
  }

    int t = 0;
    for (; t + 3 < tot; t += 2) {
        const long long stA1 = (((t + 2) & kmask) != 0) ? 64 : dAtap;
        const long long stA2 = (((t + 3) & kmask) != 0) ? 64 : dAtap;
        const long long stB1 = (((t + 3) & kmask) != 0) ? 64 : dBtap;
        const long long stB2 = (((t + 4) & kmask) != 0) ? 64 : dBtap;
        TILEBODY(0, pB0, pB2, 1, 1, stA1, stB1, 4);
        TILEBODY(1, pB1, pB0, 1, 1, stA2, stB2, 4);
        u16* tmpB = pB0; pB0 = pB2; pB2 = pB1; pB1 = tmpB;
    }
    TILEBODY(0, pB0, pB2, 1, 0, 0, 0, 0);
    TILEBODY(1, pB1, pB0, 0, 0, 0, 0, -1);
#undef READ_AQ
#undef READ_BQ
#undef MFMA_Q2
#undef TILEBODY

    if constexpr (OUTK == 4) {
        // GLU: a,b pairs in adjacent 16-col fragments; residual h_in via A operand.
        const float* bp = p.bias;
#pragma unroll
        for (int m = 0; m < 8; ++m) {
#pragma unroll
            for (int pr = 0; pr < 2; ++pr) {
                int ca = c0 + wcq * 64 + (2 * pr) * 16 + fr;
                int chan = (c0 >> 1) + wcq * 32 + pr * 16 + fr;
                float biasa = bp[ca], biasb = bp[ca + 16];
#pragma unroll
                for (int r = 0; r < 4; ++r) {
                    int row = n0 + wr * 128 + m * 16 + fq * 4 + r;
                    float a = acc[m][2 * pr][r] + biasa;
                    float bq = acc[m][2 * pr + 1][r] + biasb;
                    float sig = 1.f / (1.f + __expf(-bq));
                    float h = bf2f(Abase[(long long)row * lda + chan]);
                    ((u16*)p.out)[(long long)bz * p.o_bstride + (long long)row * p.ldc + chan]
                        = f2bf((h + a * sig) * SQRT_HALF_F);
                }
            }
        }
        return;
    } else if constexpr (OUTK == 2) {
        // f32 transposed store [col][ldc]+row, col-masked, col-bias
        const float* bias = p.bias + (long long)bz * p.bias_bstride;
#pragma unroll
        for (int m = 0; m < 8; ++m) {
#pragma unroll
            for (int n = 0; n < 4; ++n) {
                int col = c0 + wcq * 64 + n * 16 + fr;
                if (col >= p.store_ncols) continue;
                float cb = bias[col];
#pragma unroll
                for (int r = 0; r < 4; ++r) {
                    int row = n0 + wr * 128 + m * 16 + fq * 4 + r;
                    ((float*)p.out)[(long long)bz * p.o_bstride + (long long)col * p.ldc + row]
                        = acc[m][n][r] * p.scale + cb;
                }
            }
        }
        return;
    } else {
        const float* bias = p.bias ? p.bias + (long long)bz * p.bias_bstride : nullptr;
#pragma unroll
        for (int m = 0; m < 8; ++m) {
#pragma unroll
            for (int n = 0; n < 4; ++n) {
                int col = c0 + wcq * 64 + n * 16 + fr;
                float cb = (OUTK == 1 && bias) ? bias[col] : 0.f;
#pragma unroll
                for (int r = 0; r < 4; ++r) {
                    int row = n0 + wr * 128 + m * 16 + fq * 4 + r;
                    float v = acc[m][n][r] * p.scale + cb;
                    if (OUTK == 5) v += bias[row];
                    ((u16*)p.out)[(long long)bz * p.o_bstride + (long long)row * p.ldc + col]
                        = f2bf(v);
                }
            }
        }
    }
}

// ---------------- elementwise / helper kernels ----------------

// Source-coalesced GLU weight convert+permute: one thread per (l, o, i) reads the
// 5 taps contiguously (warp = dense 1280B span), writes 5 u16 planes (128B/warp each).
__global__ void cvt_glu(const float* src, u16* dst) {
    int u = blockIdx.x * 256 + threadIdx.x;          // 8*1024*512 = 4,194,304
    if (u >= 8 * 1024 * 512) return;
    int i = u & 511;
    int o = (u >> 9) & 1023;
    int l = u >> 19;
    // g = glu_perm^{-1}(o)
    int hi = o >> 9;
    int op = o & 511;
    int tile = op >> 7;
    int wcq = (op >> 5) & 3;
    int nhalf = (op >> 4) & 1;
    int fr = op & 15;
    int g = tile * 256 + wcq * 64 + (2 * nhalf + hi) * 16 + fr;
    const float* s = src + (long long)u * 5;
    long long dbase = ((long long)l * 5 * 1024 + g) * 512 + i;
#pragma unroll
    for (int k = 0; k < 5; ++k)
        dst[dbase + (long long)k * 1024 * 512] = f2bf(s[k]);
}

__global__ void perm_bias(const float* gb, float* biasP) {
    int t = blockIdx.x * 256 + threadIdx.x;
    if (t >= 8 * 1024) return;
    int g = t & 1023, l = t >> 10;
    biasP[t] = gb[l * 1024 + glu_perm(g)];
}

// All four small weight conversions in one launch (flat index with range branch).
__global__ void cvt_all(const float* enc_start_w, const float* enc_end_w,
                        const float* w_pre, const float* w_post,
                        u16* wstart, u16* wend, u16* wpre, u16* wpost) {
    int t = blockIdx.x * 256 + threadIdx.x;
    if (t < 131072) {                        // wstart: 512x240 -> 512x256
        int i = t & 255, o = t >> 8;
        wstart[t] = f2bf(i < 240 ? enc_start_w[o * 240 + i] : 0.f);
    } else if (t < 655360) {                 // wend: 1024x512 straight convert
        int q = t - 131072;
        wend[q] = f2bf(enc_end_w[q]);
    } else if (t < 786432) {                 // wpre: 512x240 -> 512x256
        int q = t - 655360;
        int i = q & 255, o = q >> 8;
        wpre[q] = f2bf(i < 240 ? w_pre[o * 240 + i] : 0.f);
    } else if (t < 1048576) {                // wpost: 240x1024 -> 256x1024
        int q = t - 786432;
        int i = q & 1023, o = q >> 10;
        wpost[q] = f2bf(o < 240 ? w_post[o * 1024 + i] : 0.f);
    }
}

// src [b][240][Len] f32 -> dst [b][Len][256] bf16 (zero-pad channels); z<16: in_s->XS, else in_t->XT
__global__ void transpose_in(const float* in_s, const float* in_t, u16* XS, u16* XT) {
    __shared__ float tile[32][33];
    int zz = blockIdx.z;
    const float* src = (zz < BB) ? in_s : in_t;
    u16* dst = (zz < BB) ? XS : XT;
    int b = zz & (BB - 1);
    int n0 = blockIdx.x * 32, c0 = blockIdx.y * 32;
    int tx = threadIdx.x, ty = threadIdx.y;
    int c = c0 + ty, n = n0 + tx;
    float v = 0.f;
    if (c < 240) v = src[((long long)b * 240 + c) * 2048 + n];
    tile[ty][tx] = v;
    __syncthreads();
    dst[((long long)b * 2048 + (n0 + ty)) * 256 + (c0 + tx)] = f2bf(tile[tx][ty]);
}

__global__ void zero_pads(u16* h0, u16* h1) {
    long long t = (long long)blockIdx.x * blockDim.x + threadIdx.x;
    const long long half = (long long)BB * 128 * 512;
    if (t >= 2 * half) return;
    u16* h = (t < half) ? h0 : h1;
    long long q = (t < half) ? t : t - half;
    int c = (int)(q % 512); long long r = q / 512;
    int rr = (int)(r % 128); int b = (int)(r / 128);
    int row = rr < HPAD ? rr : (HROWS - 128 + rr);
    h[((long long)b * HROWS + row) * 512 + c] = 0;
}

// blockIdx.y == 0: qbias (pre); == 1: ybias (post)
__global__ void bias_kernel(const float* ct,
                            const float* wcpre, const float* wpre_f, const float* bpre,
                            const float* wcpost, const float* wpost_f, const float* bpost,
                            float* qbias, float* ybias) {
    __shared__ float s[1024];
    int b = blockIdx.x; int tid = threadIdx.x;
    if (blockIdx.y == 0) {
        if (tid < 240) {
            float a = 0.f;
            for (int c = 0; c < 8; ++c) a += ct[b * 8 + c] * wcpre[c * 240 + tid];
            s[tid] = a;
        }
        __syncthreads();
        for (int o = tid; o < 512; o += 256) {
            float a = bpre[o];
            for (int d0 = 0; d0 < 240; ++d0) a += wpre_f[o * 240 + d0] * s[d0];
            qbias[b * 512 + o] = a;
        }
    } else {
        for (int e = tid; e < 1024; e += 256) {
            float a = 0.f;
            for (int c = 0; c < 8; ++c) a += ct[b * 8 + c] * wcpost[c * 1024 + e];
            s[e] = a;
        }
        __syncthreads();
        if (tid < 240) {
            float a = bpost[tid];
            for (int e = 0; e < 1024; ++e) a += wpost_f[tid * 1024 + e] * s[e];
            ybias[b * 240 + tid] = a;
        }
    }
}

// One wave per (b,t): read bf16 score row, softmax, write normalized bf16 AT row.
__global__ __launch_bounds__(256)
void softmax_rows(const u16* St, u16* AT) {
    int b = blockIdx.y;
    int t = blockIdx.x * 4 + (threadIdx.x >> 6);
    int lane = threadIdx.x & 63;
    const u16* row = St + ((long long)b * TT + t) * NN;
    short8 v[4];
#pragma unroll
    for (int i = 0; i < 4; ++i) v[i] = ((const short8*)row)[i * 64 + lane];
    float f[32];
#pragma unroll
    for (int i = 0; i < 4; ++i)
#pragma unroll
        for (int j = 0; j < 8; ++j) f[i * 8 + j] = bf2f((u16)v[i][j]);
    float m = -3.4e38f;
#pragma unroll
    for (int i = 0; i < 32; ++i) m = fmaxf(m, f[i]);
#pragma unroll
    for (int s = 1; s < 64; s <<= 1) m = fmaxf(m, __shfl_xor(m, s, 64));
    float sum = 0.f;
#pragma unroll
    for (int i = 0; i < 32; ++i) { f[i] = __expf(f[i] - m); sum += f[i]; }
#pragma unroll
    for (int s = 1; s < 64; s <<= 1) sum += __shfl_xor(sum, s, 64);
    float li = 1.f / sum;
    u16* atrow = AT + ((long long)b * TT + t) * NN;
#pragma unroll
    for (int i = 0; i < 4; ++i) {
        short8 pk;
#pragma unroll
        for (int j = 0; j < 8; ++j) pk[j] = (short)f2bf(f[i * 8 + j] * li);
        ((short8*)atrow)[i * 64 + lane] = pk;
    }
}

// AT bf16 [b][t][n] -> A f32 [b][n][t] (final output region; Sbf is dead by now)
__global__ void transpose_out(const u16* AT, float* A) {
    __shared__ float tile[32][33];
    int b = blockIdx.z;
    int n0 = blockIdx.x * 32, t0 = blockIdx.y * 32;
    int tx = threadIdx.x, ty = threadIdx.y;
#pragma unroll
    for (int k = 0; k < 4; ++k) {
        int t = t0 + ty + k * 8;
        tile[ty + k * 8][tx] = bf2f(AT[((long long)b * TT + t) * NN + n0 + tx]);
    }
    __syncthreads();
#pragma unroll
    for (int k = 0; k < 4; ++k) {
        int n = n0 + ty + k * 8;
        A[((long long)b * NN + n) * TT + t0 + tx] = tile[tx][ty + k * 8];
    }
}

// ---------------- host orchestration ----------------

extern "C" void kernel_launch(void* const* d_in, const int* in_sizes, int n_in,
                              void* d_out, int out_size, void* d_ws, size_t ws_size,
                              hipStream_t stream) {
    const float* in_s        = (const float*)d_in[0];
    const float* in_t        = (const float*)d_in[1];
    const float* c_t         = (const float*)d_in[2];
    const float* enc_start_w = (const float*)d_in[3];
    const float* enc_start_b = (const float*)d_in[4];
    const float* glu_w       = (const float*)d_in[5];
    const float* glu_b       = (const float*)d_in[6];
    const float* enc_end_w   = (const float*)d_in[7];
    const float* enc_end_b   = (const float*)d_in[8];
    const float* wc_pre      = (const float*)d_in[9];
    const float* w_pre       = (const float*)d_in[10];
    const float* b_pre       = (const float*)d_in[11];
    const float* wc_post     = (const float*)d_in[12];
    const float* w_post      = (const float*)d_in[13];
    const float* b_post      = (const float*)d_in[14];

    // workspace layout
    char* w = (char*)d_ws;
    u16* wglu   = (u16*)w; w += 8LL * 5 * 1024 * 512 * 2;
    u16* wstart = (u16*)w; w += 512LL * 256 * 2;
    u16* wend   = (u16*)w; w += 1024LL * 512 * 2;
    u16* wpre   = (u16*)w; w += 512LL * 256 * 2;
    u16* wpost  = (u16*)w; w += 256LL * 1024 * 2;
    u16* XS     = (u16*)w; w += (long long)BB * NN * 256 * 2;
    u16* XT     = (u16*)w; w += (long long)BB * TT * 256 * 2;
    u16* h0     = (u16*)w; w += (long long)BB * HROWS * 512 * 2;
    u16* h1     = (u16*)w; w += (long long)BB * HROWS * 512 * 2;
    u16* Kb     = (u16*)w; w += (long long)BB * NN * 512 * 2;
    u16* Vb     = (u16*)w; w += (long long)BB * 512 * NN * 2;
    u16* Rc     = (u16*)w; w += (long long)BB * TT * 1024 * 2;
    u16* ATb    = (u16*)w; w += (long long)BB * TT * NN * 2;
    float* qbias = (float*)w; w += 16LL * 512 * 4;
    float* ybias = (float*)w; w += 16LL * 256 * 4;
    float* biasP = (float*)w; w += 8LL * 1024 * 4;
    if ((size_t)(w - (char*)d_ws) > ws_size) return;  // insufficient scratch — bail

    float* yout = (float*)d_out;
    float* Areg = yout + Y_SIZE;       // final A f32 [b][n][t]
    u16* Sbf = (u16*)Areg;             // transient bf16 scores [b][t][n] (dead before Areg written)

    // ---- conversions / setup (merged launches) ----
    cvt_glu<<<(8 * 1024 * 512) / 256, 256, 0, stream>>>(glu_w, wglu);
    perm_bias<<<(8 * 1024 + 255) / 256, 256, 0, stream>>>(glu_b, biasP);
    cvt_all<<<1048576 / 256, 256, 0, stream>>>(enc_start_w, enc_end_w, w_pre, w_post,
                                               wstart, wend, wpre, wpost);
    transpose_in<<<dim3(NN / 32, 256 / 32, 2 * BB), dim3(32, 32), 0, stream>>>(in_s, in_t, XS, XT);
    zero_pads<<<(2LL * BB * 128 * 512 + 255) / 256, 256, 0, stream>>>(h0, h1);
    bias_kernel<<<dim3(16, 2), 256, 0, stream>>>(c_t, wc_pre, w_pre, b_pre,
                                                 wc_post, w_post, b_post, qbias, ybias);

    // ---- enc_start: XS[2048][256] x wstart[512][256] -> h0 bf16 [n][512] ----
    {
        GemmP p{}; p.A = XS; p.a_bstride = (long long)NN * 256; p.lda = 256;
        p.Bw = wstart; p.b_bstride = 0; p.b_tapstride = 0; p.ldb = 256;
        p.ntaps = 1; p.shift0 = 0; p.dshift = 0; p.Kt = 256; p.ks_log2 = 2;
        p.out = h0 + HPAD * 512; p.o_bstride = (long long)HROWS * 512; p.ldc = 512;
        p.bias = enc_start_b; p.bias_bstride = 0; p.scale = 1.f; p.store_ncols = 512;
        gemm256<1><<<8 * 2 * 16, 512, 0, stream>>>(p, 8, 2);
    }

    // ---- 8 GLU blocks (fused epilogue) ----
    const int dils[8] = {1, 3, 9, 27, 1, 3, 9, 27};
    u16* hin = h0; u16* hout = h1;
    for (int l = 0; l < 8; ++l) {
        GemmP q{}; q.A = hin + HPAD * 512; q.a_bstride = (long long)HROWS * 512; q.lda = 512;
        q.Bw = wglu + (long long)l * 5 * 1024 * 512; q.b_bstride = 0;
        q.b_tapstride = 1024LL * 512; q.ldb = 512;
        q.ntaps = 5; q.shift0 = -2 * dils[l]; q.dshift = dils[l]; q.Kt = 512; q.ks_log2 = 3;
        q.out = hout + HPAD * 512; q.o_bstride = (long long)HROWS * 512; q.ldc = 512;
        q.bias = biasP + l * 1024; q.bias_bstride = 0; q.scale = 1.f; q.store_ncols = 1024;
        gemm256<4><<<8 * 4 * 16, 512, 0, stream>>>(q, 8, 4);
        u16* tmp = hin; hin = hout; hout = tmp;
    }

    // ---- enc_end K: h[n][512] x wend_K[512][512] -> Kb bf16 [n][512] ----
    {
        GemmP p{}; p.A = hin + HPAD * 512; p.a_bstride = (long long)HROWS * 512; p.lda = 512;
        p.Bw = wend; p.b_bstride = 0; p.b_tapstride = 0; p.ldb = 512;
        p.ntaps = 1; p.shift0 = 0; p.dshift = 0; p.Kt = 512; p.ks_log2 = 3;
        p.out = Kb; p.o_bstride = (long long)NN * 512; p.ldc = 512;
        p.bias = enc_end_b; p.bias_bstride = 0; p.scale = 1.f; p.store_ncols = 512;
        gemm256<1><<<8 * 2 * 16, 512, 0, stream>>>(p, 8, 2);
    }
    // ---- enc_end V (operand-swapped): Vb[d][n] = wend_V[d][k] · h[n][k], row-bias ----
    {
        GemmP p{}; p.A = wend + 512LL * 512; p.a_bstride = 0; p.lda = 512;
        p.Bw = hin + HPAD * 512; p.b_bstride = (long long)HROWS * 512; p.b_tapstride = 0; p.ldb = 512;
        p.ntaps = 1; p.shift0 = 0; p.dshift = 0; p.Kt = 512; p.ks_log2 = 3;
        p.out = Vb; p.o_bstride = 512LL * NN; p.ldc = NN;
        p.bias = enc_end_b + 512; p.bias_bstride = 0; p.scale = 1.f; p.store_ncols = NN;
        gemm256<5><<<2 * 8 * 16, 512, 0, stream>>>(p, 2, 8);
    }

    // ---- pre-decoder: Q into Rc columns 512..1023 ----
    {
        GemmP p{}; p.A = XT; p.a_bstride = (long long)TT * 256; p.lda = 256;
        p.Bw = wpre; p.b_bstride = 0; p.b_tapstride = 0; p.ldb = 256;
        p.ntaps = 1; p.shift0 = 0; p.dshift = 0; p.Kt = 256; p.ks_log2 = 2;
        p.out = Rc + 512; p.o_bstride = (long long)TT * 1024; p.ldc = 1024;
        p.bias = qbias; p.bias_bstride = 512; p.scale = 1.f; p.store_ncols = 512;
        gemm256<1><<<8 * 2 * 16, 512, 0, stream>>>(p, 8, 2);
    }

    // ---- scores: St[t][n] = Q[t]·K[n] / sqrt(d), bf16 into Sbf ----
    {
        GemmP p{}; p.A = Rc + 512; p.a_bstride = (long long)TT * 1024; p.lda = 1024;
        p.Bw = Kb; p.b_bstride = (long long)NN * 512; p.b_tapstride = 0; p.ldb = 512;
        p.ntaps = 1; p.shift0 = 0; p.dshift = 0; p.Kt = 512; p.ks_log2 = 3;
        p.out = Sbf; p.o_bstride = (long long)TT * NN; p.ldc = NN;
        p.bias = nullptr; p.bias_bstride = 0; p.scale = 0.04419417382415922f; // 1/sqrt(512)
        p.store_ncols = NN;
        gemm256<1><<<8 * 8 * 16, 512, 0, stream>>>(p, 8, 8);
    }

    // ---- softmax over n (contiguous), normalized AT bf16; then AT -> A f32 ----
    softmax_rows<<<dim3(TT / 4, BB), 256, 0, stream>>>(Sbf, ATb);
    transpose_out<<<dim3(NN / 32, TT / 32, BB), dim3(32, 8), 0, stream>>>(ATb, Areg);

    // ---- R = V x A  (C[t][d] = sum_n AT[t][n] * V[d][n]) into Rc cols 0..511 ----
    {
        GemmP p{}; p.A = ATb; p.a_bstride = (long long)TT * NN; p.lda = NN;
        p.Bw = Vb; p.b_bstride = 512LL * NN; p.b_tapstride = 0; p.ldb = NN;
        p.ntaps = 1; p.shift0 = 0; p.dshift = 0; p.Kt = NN; p.ks_log2 = 5;
        p.out = Rc; p.o_bstride = (long long)TT * 1024; p.ldc = 1024;
        p.bias = nullptr; p.bias_bstride = 0; p.scale = 1.f; p.store_ncols = 512;
        gemm256<1><<<8 * 2 * 16, 512, 0, stream>>>(p, 8, 2);
    }

    // ---- post-decoder: Rc[t][1024] x wpost -> y f32 [b][240][t] (transposed store) ----
    {
        GemmP p{}; p.A = Rc; p.a_bstride = (long long)TT * 1024; p.lda = 1024;
        p.Bw = wpost; p.b_bstride = 0; p.b_tapstride = 0; p.ldb = 1024;
        p.ntaps = 1; p.shift0 = 0; p.dshift = 0; p.Kt = 1024; p.ks_log2 = 4;
        p.out = yout; p.o_bstride = (long long)DIN * TT; p.ldc = TT;
        p.bias = ybias; p.bias_bstride = 240; p.scale = 1.f; p.store_ncols = 240;
        gemm256<2><<<8 * 1 * 16, 512, 0, stream>>>(p, 8, 1);
    }
}